// Round 1
// baseline (1794.600 us; speedup 1.0000x reference)
//
#include <hip/hip_runtime.h>
#include <math.h>

#define BSZ 2
#define SEQ 2048
#define DIM 1024
#define NH 16
#define HDIM 64
#define MR (BSZ*SEQ)   // 4096 rows

// ---------------------------------------------------------------------------
// GEMM NT: C[M,N] = A[M,K] * B[N,K]^T   (M=4096, N=K=1024, all fp32)
// 64x64 block tile, 256 threads, 4x4 per thread, KT=16 LDS staging.
// ---------------------------------------------------------------------------
__global__ __launch_bounds__(256)
void gemm_nt(const float* __restrict__ A, const float* __restrict__ Bw,
             float* __restrict__ C)
{
    const int K = DIM, N = DIM;
    __shared__ float As[16][68];   // [k][row], stride 68 floats = 16B aligned
    __shared__ float Bs[16][68];   // [k][col]
    const int tid  = threadIdx.x;
    const int tx   = tid & 15;      // col group (4 cols)
    const int ty   = tid >> 4;      // row group (4 rows)
    const int lrow = tid >> 2;      // loader row 0..63
    const int lk   = (tid & 3) << 2; // loader k offset 0,4,8,12
    const int rowBase = blockIdx.y << 6;
    const int colBase = blockIdx.x << 6;
    const float* Ap = A  + (size_t)(rowBase + lrow) * K + lk;
    const float* Bp = Bw + (size_t)(colBase + lrow) * K + lk;
    float acc[4][4] = {};
    for (int k0 = 0; k0 < K; k0 += 16) {
        float4 a4 = *(const float4*)(Ap + k0);
        float4 b4 = *(const float4*)(Bp + k0);
        __syncthreads();   // previous iteration's LDS reads complete
        As[lk+0][lrow]=a4.x; As[lk+1][lrow]=a4.y; As[lk+2][lrow]=a4.z; As[lk+3][lrow]=a4.w;
        Bs[lk+0][lrow]=b4.x; Bs[lk+1][lrow]=b4.y; Bs[lk+2][lrow]=b4.z; Bs[lk+3][lrow]=b4.w;
        __syncthreads();
#pragma unroll
        for (int kk = 0; kk < 16; ++kk) {
            float4 av = *(const float4*)&As[kk][ty<<2];
            float4 bv = *(const float4*)&Bs[kk][tx<<2];
            acc[0][0] += av.x*bv.x; acc[0][1] += av.x*bv.y; acc[0][2] += av.x*bv.z; acc[0][3] += av.x*bv.w;
            acc[1][0] += av.y*bv.x; acc[1][1] += av.y*bv.y; acc[1][2] += av.y*bv.z; acc[1][3] += av.y*bv.w;
            acc[2][0] += av.z*bv.x; acc[2][1] += av.z*bv.y; acc[2][2] += av.z*bv.z; acc[2][3] += av.z*bv.w;
            acc[3][0] += av.w*bv.x; acc[3][1] += av.w*bv.y; acc[3][2] += av.w*bv.z; acc[3][3] += av.w*bv.w;
        }
    }
    float* Cp = C + (size_t)(rowBase + (ty<<2)) * N + colBase + (tx<<2);
#pragma unroll
    for (int i = 0; i < 4; ++i) {
        float4 o4; o4.x=acc[i][0]; o4.y=acc[i][1]; o4.z=acc[i][2]; o4.w=acc[i][3];
        *(float4*)(Cp + (size_t)i * N) = o4;
    }
}

// ---------------------------------------------------------------------------
// def_w[b,h,s] = sum_t sigmoid( (q_def[b,h,s,:] . k_def[b,h,t,:]) / 8 )
// grid (SEQ/64, BSZ*NH), 256 threads, 64-query tile vs all 2048 keys.
// ---------------------------------------------------------------------------
__global__ __launch_bounds__(256)
void defw_kernel(const float* __restrict__ qd, const float* __restrict__ kd,
                 float* __restrict__ defw)
{
    __shared__ float Qs[64][68];   // [e][row]  (transposed)
    __shared__ float Ks[64][68];   // [e][col]
    const int tid = threadIdx.x;
    const int tx = tid & 15, ty = tid >> 4;
    const int bh = blockIdx.y;
    const int b = bh >> 4, h = bh & 15;
    const int qbase = blockIdx.x << 6;
    const int lrow = tid >> 2;          // 0..63
    const int le   = (tid & 3) << 4;    // 0,16,32,48
    {
        const float* qp = qd + ((size_t)(b*SEQ + qbase + lrow))*DIM + h*HDIM + le;
#pragma unroll
        for (int u = 0; u < 4; ++u) {
            float4 v4 = *(const float4*)(qp + (u<<2));
            Qs[le+(u<<2)+0][lrow]=v4.x; Qs[le+(u<<2)+1][lrow]=v4.y;
            Qs[le+(u<<2)+2][lrow]=v4.z; Qs[le+(u<<2)+3][lrow]=v4.w;
        }
    }
    float rs[4] = {0.f,0.f,0.f,0.f};
    for (int kt = 0; kt < SEQ; kt += 64) {
        __syncthreads();   // prev compute done (also covers Q-load on iter 0)
        {
            const float* kp = kd + ((size_t)(b*SEQ + kt + lrow))*DIM + h*HDIM + le;
#pragma unroll
            for (int u = 0; u < 4; ++u) {
                float4 v4 = *(const float4*)(kp + (u<<2));
                Ks[le+(u<<2)+0][lrow]=v4.x; Ks[le+(u<<2)+1][lrow]=v4.y;
                Ks[le+(u<<2)+2][lrow]=v4.z; Ks[le+(u<<2)+3][lrow]=v4.w;
            }
        }
        __syncthreads();
        float acc[4][4] = {};
#pragma unroll 8
        for (int e = 0; e < 64; ++e) {
            float4 qv = *(const float4*)&Qs[e][ty<<2];
            float4 kv = *(const float4*)&Ks[e][tx<<2];
            acc[0][0] += qv.x*kv.x; acc[0][1] += qv.x*kv.y; acc[0][2] += qv.x*kv.z; acc[0][3] += qv.x*kv.w;
            acc[1][0] += qv.y*kv.x; acc[1][1] += qv.y*kv.y; acc[1][2] += qv.y*kv.z; acc[1][3] += qv.y*kv.w;
            acc[2][0] += qv.z*kv.x; acc[2][1] += qv.z*kv.y; acc[2][2] += qv.z*kv.z; acc[2][3] += qv.z*kv.w;
            acc[3][0] += qv.w*kv.x; acc[3][1] += qv.w*kv.y; acc[3][2] += qv.w*kv.z; acc[3][3] += qv.w*kv.w;
        }
#pragma unroll
        for (int i = 0; i < 4; ++i)
#pragma unroll
            for (int j = 0; j < 4; ++j) {
                float x = acc[i][j] * 0.125f;
                rs[i] += 1.0f / (1.0f + __expf(-x));
            }
    }
#pragma unroll
    for (int i = 0; i < 4; ++i) {
        float vsum = rs[i];
        vsum += __shfl_xor(vsum, 8, 16);
        vsum += __shfl_xor(vsum, 4, 16);
        vsum += __shfl_xor(vsum, 2, 16);
        vsum += __shfl_xor(vsum, 1, 16);
        if (tx == 0) defw[(size_t)bh*SEQ + qbase + (ty<<2) + i] = vsum;
    }
}

// ---------------------------------------------------------------------------
// Flash attention with per-key defeasible weight:
//   z[s,t] = (q.k)/8 * defw[t];  attn = softmax_t(z);  O = attn @ V
// grid (SEQ/64, BSZ*NH), 256 threads, 64-query tile, online softmax.
// ---------------------------------------------------------------------------
__global__ __launch_bounds__(256)
void flash_kernel(const float* __restrict__ q, const float* __restrict__ k,
                  const float* __restrict__ v, const float* __restrict__ defw,
                  float* __restrict__ o)
{
    __shared__ float Qs[64][68];   // [e][row]
    __shared__ float KV[64][68];   // phase 1: K as [e][col]; phase 2: V as [t][d]
    __shared__ float Ss[64][68];   // scores z, then P   [row][col]
    const int tid = threadIdx.x;
    const int tx = tid & 15, ty = tid >> 4;
    const int bh = blockIdx.y;
    const int b = bh >> 4, h = bh & 15;
    const int qbase = blockIdx.x << 6;
    const int lrow = tid >> 2;        // loader / softmax row 0..63
    const int le   = (tid & 3) << 4;  // loader e / softmax-PV d-group base
    // load Q tile transposed (once)
    {
        const float* qp = q + ((size_t)(b*SEQ + qbase + lrow))*DIM + h*HDIM + le;
#pragma unroll
        for (int u = 0; u < 4; ++u) {
            float4 v4 = *(const float4*)(qp + (u<<2));
            Qs[le+(u<<2)+0][lrow]=v4.x; Qs[le+(u<<2)+1][lrow]=v4.y;
            Qs[le+(u<<2)+2][lrow]=v4.z; Qs[le+(u<<2)+3][lrow]=v4.w;
        }
    }
    float O[16];
#pragma unroll
    for (int u = 0; u < 16; ++u) O[u] = 0.f;
    float m_run = -1e30f, l_run = 0.f;

    for (int kt = 0; kt < SEQ; kt += 64) {
        __syncthreads();   // (a) prev PV reads of KV/Ss complete; Q visible on iter 0
        {   // load K tile transposed
            const float* kp = k + ((size_t)(b*SEQ + kt + lrow))*DIM + h*HDIM + le;
#pragma unroll
            for (int u = 0; u < 4; ++u) {
                float4 v4 = *(const float4*)(kp + (u<<2));
                KV[le+(u<<2)+0][lrow]=v4.x; KV[le+(u<<2)+1][lrow]=v4.y;
                KV[le+(u<<2)+2][lrow]=v4.z; KV[le+(u<<2)+3][lrow]=v4.w;
            }
        }
        __syncthreads();   // (b) K visible
        float acc[4][4] = {};
#pragma unroll 8
        for (int e = 0; e < 64; ++e) {
            float4 qv = *(const float4*)&Qs[e][ty<<2];
            float4 kv = *(const float4*)&KV[e][tx<<2];
            acc[0][0] += qv.x*kv.x; acc[0][1] += qv.x*kv.y; acc[0][2] += qv.x*kv.z; acc[0][3] += qv.x*kv.w;
            acc[1][0] += qv.y*kv.x; acc[1][1] += qv.y*kv.y; acc[1][2] += qv.y*kv.z; acc[1][3] += qv.y*kv.w;
            acc[2][0] += qv.z*kv.x; acc[2][1] += qv.z*kv.y; acc[2][2] += qv.z*kv.z; acc[2][3] += qv.z*kv.w;
            acc[3][0] += qv.w*kv.x; acc[3][1] += qv.w*kv.y; acc[3][2] += qv.w*kv.z; acc[3][3] += qv.w*kv.w;
        }
        float wj[4];
#pragma unroll
        for (int j = 0; j < 4; ++j)
            wj[j] = defw[(size_t)bh*SEQ + kt + (tx<<2) + j];
#pragma unroll
        for (int i = 0; i < 4; ++i)
#pragma unroll
            for (int j = 0; j < 4; ++j)
                Ss[(ty<<2)+i][(tx<<2)+j] = acc[i][j] * 0.125f * wj[j];
        __syncthreads();   // (c) scores visible; K reads done
        {   // load V tile natural layout [t][d]
            const float* vp = v + ((size_t)(b*SEQ + kt + lrow))*DIM + h*HDIM + le;
#pragma unroll
            for (int u = 0; u < 4; ++u) {
                float4 v4 = *(const float4*)(vp + (u<<2));
                *(float4*)&KV[lrow][le+(u<<2)] = v4;
            }
        }
        // online softmax: thread handles row=lrow, cols le..le+15
        float zt[16];
#pragma unroll
        for (int u = 0; u < 4; ++u) {
            float4 z4 = *(const float4*)&Ss[lrow][le+(u<<2)];
            zt[(u<<2)+0]=z4.x; zt[(u<<2)+1]=z4.y; zt[(u<<2)+2]=z4.z; zt[(u<<2)+3]=z4.w;
        }
        float tmax = zt[0];
#pragma unroll
        for (int u = 1; u < 16; ++u) tmax = fmaxf(tmax, zt[u]);
        tmax = fmaxf(tmax, __shfl_xor(tmax, 1, 4));
        tmax = fmaxf(tmax, __shfl_xor(tmax, 2, 4));
        float m_new = fmaxf(m_run, tmax);
        float alpha = __expf(m_run - m_new);
        float lsum = 0.f;
#pragma unroll
        for (int u = 0; u < 16; ++u) { zt[u] = __expf(zt[u] - m_new); lsum += zt[u]; }
#pragma unroll
        for (int u = 0; u < 4; ++u) {
            float4 p4; p4.x=zt[(u<<2)+0]; p4.y=zt[(u<<2)+1]; p4.z=zt[(u<<2)+2]; p4.w=zt[(u<<2)+3];
            *(float4*)&Ss[lrow][le+(u<<2)] = p4;
        }
        lsum += __shfl_xor(lsum, 1, 4);
        lsum += __shfl_xor(lsum, 2, 4);
        l_run = l_run * alpha + lsum;
        m_run = m_new;
#pragma unroll
        for (int u = 0; u < 16; ++u) O[u] *= alpha;
        __syncthreads();   // (d) P and V visible
#pragma unroll 8
        for (int c = 0; c < 64; ++c) {
            float p = Ss[lrow][c];
            float4 v0 = *(const float4*)&KV[c][le+0];
            float4 v1 = *(const float4*)&KV[c][le+4];
            float4 v2 = *(const float4*)&KV[c][le+8];
            float4 v3 = *(const float4*)&KV[c][le+12];
            O[0]+=p*v0.x;  O[1]+=p*v0.y;  O[2]+=p*v0.z;  O[3]+=p*v0.w;
            O[4]+=p*v1.x;  O[5]+=p*v1.y;  O[6]+=p*v1.z;  O[7]+=p*v1.w;
            O[8]+=p*v2.x;  O[9]+=p*v2.y;  O[10]+=p*v2.z; O[11]+=p*v2.w;
            O[12]+=p*v3.x; O[13]+=p*v3.y; O[14]+=p*v3.z; O[15]+=p*v3.w;
        }
    }
    float inv = 1.0f / l_run;
    float* op = o + ((size_t)(b*SEQ + qbase + lrow))*DIM + h*HDIM + le;
#pragma unroll
    for (int u = 0; u < 4; ++u) {
        float4 o4;
        o4.x=O[(u<<2)+0]*inv; o4.y=O[(u<<2)+1]*inv; o4.z=O[(u<<2)+2]*inv; o4.w=O[(u<<2)+3]*inv;
        *(float4*)(op + (u<<2)) = o4;
    }
}

// ---------------------------------------------------------------------------
extern "C" void kernel_launch(void* const* d_in, const int* in_sizes, int n_in,
                              void* d_out, int out_size, void* d_ws, size_t ws_size,
                              hipStream_t stream)
{
    (void)in_sizes; (void)n_in; (void)out_size; (void)ws_size;
    const float* qi     = (const float*)d_in[0];
    const float* ki     = (const float*)d_in[1];
    const float* vi     = (const float*)d_in[2];
    const float* Wq     = (const float*)d_in[3];
    const float* Wq_def = (const float*)d_in[4];
    const float* Wk     = (const float*)d_in[5];
    const float* Wk_def = (const float*)d_in[6];
    const float* Wv     = (const float*)d_in[7];
    const float* Wo     = (const float*)d_in[8];
    float* out = (float*)d_out;

    const size_t NB = (size_t)MR * DIM;   // 4,194,304 floats = 16 MiB
    float* bufA = (float*)d_ws;           // q
    float* bufB = bufA + NB;              // k
    float* bufC = bufB + NB;              // q_def, later v
    float* bufD = bufC + NB;              // k_def, later attended
    float* dw   = bufD + NB;              // def_w [BSZ*NH*SEQ]

    dim3 gGemm(DIM/64, MR/64);            // (16, 64)
    dim3 gAttn(SEQ/64, BSZ*NH);           // (32, 32)

    // defeasible path first so its buffers can be reused
    gemm_nt<<<gGemm, 256, 0, stream>>>(qi, Wq_def, bufC);
    gemm_nt<<<gGemm, 256, 0, stream>>>(ki, Wk_def, bufD);
    defw_kernel<<<gAttn, 256, 0, stream>>>(bufC, bufD, dw);
    // main projections (bufC/bufD free now)
    gemm_nt<<<gGemm, 256, 0, stream>>>(qi, Wq, bufA);
    gemm_nt<<<gGemm, 256, 0, stream>>>(ki, Wk, bufB);
    gemm_nt<<<gGemm, 256, 0, stream>>>(vi, Wv, bufC);
    // attention -> bufD (attended, [B,S,D] with head-major inner layout)
    flash_kernel<<<gAttn, 256, 0, stream>>>(bufA, bufB, bufC, dw, bufD);
    // output projection
    gemm_nt<<<gGemm, 256, 0, stream>>>(bufD, Wo, out);
}